// Round 2
// baseline (4672.800 us; speedup 1.0000x reference)
//
#include <hip/hip_runtime.h>
#include <hip/hip_bf16.h>
#include <math.h>

// Problem constants
#define LL 2048
#define DD 256
#define MTOT 8192       // B*L
#define DINNER 512

__device__ __forceinline__ float us2f(unsigned short u){
  return __uint_as_float(((unsigned)u) << 16);
}

// ---- dtype probe: mf_Alog[0][0]=log(1)=0, [0][1]=log(2)!=0.
// fp32 word0 == 0x00000000 ; bf16 word0 == 0x3F310000  => word0!=0 <=> bf16
__global__ void probe_kernel(const unsigned* __restrict__ alog, int* __restrict__ flag){
  if (threadIdx.x == 0 && blockIdx.x == 0) *flag = (alog[0] != 0u) ? 1 : 0;
}

struct Srcs { const void* p[32]; unsigned off[33]; };

// Convert all 32 weight tensors (inputs 1..32) into packed fp32 at dst.
__global__ __launch_bounds__(256) void cvt_all_kernel(Srcs s, float* __restrict__ dst,
                                                      const int* __restrict__ flag,
                                                      unsigned total){
  unsigned i = blockIdx.x * 256u + threadIdx.x;
  if (i >= total) return;
  int k = 31;
  while (s.off[k] > i) --k;
  unsigned j = i - s.off[k];
  if (*flag) dst[i] = us2f(((const unsigned short*)s.p[k])[j]);
  else       dst[i] = ((const float*)s.p[k])[j];
}

// Convert x (input 0) to fp32 residual buffer.
__global__ __launch_bounds__(256) void cvt_x_kernel(const void* __restrict__ src,
                                                    float* __restrict__ dst,
                                                    const int* __restrict__ flag, unsigned n){
  unsigned i = blockIdx.x * 256u + threadIdx.x;
  if (i >= n) return;
  if (*flag) dst[i] = us2f(((const unsigned short*)src)[i]);
  else       dst[i] = ((const float*)src)[i];
}

enum { M_PLAIN=0, M_BIAS=1, M_SOFTPLUS=2, M_GELU=3, M_RESID=4, M_FINAL=5 };

// C[M,N] = epilogue( A[M,K](fp32,row,lda) * W[N,K](fp32,row)^T + bias )
// 64x64 tile, 256 threads, 4x4 microtile, BK=16.
__global__ __launch_bounds__(256) void gemm_kernel(
    const float* __restrict__ A, int lda,
    const float* __restrict__ W,
    const float* __restrict__ bias,
    float* __restrict__ C,
    float* __restrict__ resid,
    void* __restrict__ outb,
    const int* __restrict__ flag,
    int N, int K, int mode)
{
  __shared__ float sA[16][64];
  __shared__ float sB[16][64];
  const int tid = threadIdx.x;
  const int m0 = blockIdx.y << 6, n0 = blockIdx.x << 6;
  const int lr = tid >> 2, kq = tid & 3;   // loader: row-in-tile, k-quad
  const int tm = tid & 15, tn = tid >> 4;  // compute: 4x4 microtile coords
  const int wrow = n0 + lr;
  float acc[4][4] = {};
  for (int k0 = 0; k0 < K; k0 += 16){
    float4 av = *(const float4*)(A + (size_t)(m0 + lr) * lda + k0 + (kq << 2));
    float4 bv = make_float4(0.f, 0.f, 0.f, 0.f);
    if (wrow < N)
      bv = *(const float4*)(W + (size_t)wrow * K + k0 + (kq << 2));
    __syncthreads();
    const int kb = kq << 2;
    sA[kb+0][lr] = av.x; sA[kb+1][lr] = av.y; sA[kb+2][lr] = av.z; sA[kb+3][lr] = av.w;
    sB[kb+0][lr] = bv.x; sB[kb+1][lr] = bv.y; sB[kb+2][lr] = bv.z; sB[kb+3][lr] = bv.w;
    __syncthreads();
    #pragma unroll
    for (int k = 0; k < 16; ++k){
      float4 a4 = *(const float4*)&sA[k][tm << 2];
      float4 b4 = *(const float4*)&sB[k][tn << 2];
      float a[4] = {a4.x, a4.y, a4.z, a4.w};
      float b[4] = {b4.x, b4.y, b4.z, b4.w};
      #pragma unroll
      for (int i = 0; i < 4; ++i)
        #pragma unroll
        for (int j = 0; j < 4; ++j)
          acc[i][j] = fmaf(a[i], b[j], acc[i][j]);
    }
  }
  const int nc = n0 + (tn << 2);
  if (nc >= N) return;   // all N are multiples of 4; per-thread all-or-nothing
  float b4v[4] = {0.f, 0.f, 0.f, 0.f};
  if (bias){
    #pragma unroll
    for (int j = 0; j < 4; ++j) b4v[j] = bias[nc + j];
  }
  #pragma unroll
  for (int i = 0; i < 4; ++i){
    const int m = m0 + (tm << 2) + i;
    const size_t off = (size_t)m * N + nc;
    float r[4];
    #pragma unroll
    for (int j = 0; j < 4; ++j) r[j] = acc[i][j] + b4v[j];
    if (mode == M_SOFTPLUS){
      #pragma unroll
      for (int j = 0; j < 4; ++j) r[j] = (r[j] > 20.f) ? r[j] : log1pf(expf(r[j]));
      *(float4*)(C + off) = make_float4(r[0], r[1], r[2], r[3]);
    } else if (mode == M_GELU){
      #pragma unroll
      for (int j = 0; j < 4; ++j) r[j] = 0.5f * r[j] * (1.f + erff(r[j] * 0.70710678118f));
      *(float4*)(C + off) = make_float4(r[0], r[1], r[2], r[3]);
    } else if (mode == M_RESID){
      #pragma unroll
      for (int j = 0; j < 4; ++j) resid[off + j] += r[j];
    } else if (mode == M_FINAL){
      if (*flag){
        #pragma unroll
        for (int j = 0; j < 4; ++j)
          ((__hip_bfloat16*)outb)[off + j] = __float2bfloat16(resid[off + j] + r[j]);
      } else {
        #pragma unroll
        for (int j = 0; j < 4; ++j)
          ((float*)outb)[off + j] = resid[off + j] + r[j];
      }
    } else { // PLAIN / BIAS
      *(float4*)(C + off) = make_float4(r[0], r[1], r[2], r[3]);
    }
  }
}

// LayerNorm over D=256 (fp32 in, fp32 out). One block per row, thread = channel.
__global__ __launch_bounds__(256) void ln_kernel(
    const float* __restrict__ xin,
    const float* __restrict__ w, const float* __restrict__ b,
    float* __restrict__ hout)
{
  const int row = blockIdx.x, tid = threadIdx.x;
  const size_t off = (size_t)row * DD + tid;
  float v = xin[off];
  float s = v, s2 = v * v;
  #pragma unroll
  for (int o = 32; o; o >>= 1){ s += __shfl_xor(s, o); s2 += __shfl_xor(s2, o); }
  __shared__ float ls[4], ls2[4];
  if ((tid & 63) == 0){ ls[tid >> 6] = s; ls2[tid >> 6] = s2; }
  __syncthreads();
  s  = ls[0] + ls[1] + ls[2] + ls[3];
  s2 = ls2[0] + ls2[1] + ls2[2] + ls2[3];
  const float mu  = s * (1.f / DD);
  const float var = s2 * (1.f / DD) - mu * mu;
  const float inv = rsqrtf(var + 1e-5f);
  hout[off] = (v - mu) * inv * w[tid] + b[tid];
}

// Depthwise causal conv (D_CONV=4) + bias + SiLU.
// rev=0: y[t] = sum_k w[k]*x[t-3+k]; rev=1 (flip-conv-flip folded):
// y[t] = sum_j w[3-j]*x[t+j].  Input = xz[...,0:512] (row stride 1024).
__global__ __launch_bounds__(256) void conv_silu_kernel(
    const float* __restrict__ xz, const float* __restrict__ convw,
    const float* __restrict__ convb, float* __restrict__ xi, int rev)
{
  const int idx = blockIdx.x * 256 + threadIdx.x;   // (b*2048+t)*512 + c
  const int c = idx & 511;
  const int t = (idx >> 9) & 2047;
  const int b = idx >> 20;
  float acc = convb[c];
  if (!rev){
    #pragma unroll
    for (int k = 0; k < 4; ++k){
      int tt = t - 3 + k;
      if (tt >= 0) acc += convw[c*4 + k] * xz[((size_t)(b*2048 + tt))*1024 + c];
    }
  } else {
    #pragma unroll
    for (int j = 0; j < 4; ++j){
      int tt = t + j;
      if (tt < 2048) acc += convw[c*4 + 3 - j] * xz[((size_t)(b*2048 + tt))*1024 + c];
    }
  }
  xi[idx] = acc / (1.f + expf(-acc));
}

// Selective scan. Thread = (b, d, n); n = lane%16. Shuffle-reduce over n.
// ys[b,t,d] = (sum_n h*C + u*Dp) * silu(z).  ys may alias xi (same-address
// read-before-write within one lockstep iteration).
__global__ __launch_bounds__(256) void scan_kernel(
    const float* __restrict__ dtb, const float* __restrict__ xib,
    const float* __restrict__ dblb, const float* __restrict__ xzb,
    const float* __restrict__ Alog, const float* __restrict__ Dp,
    float* __restrict__ ys, int rev)
{
  const int g = blockIdx.x * 256 + threadIdx.x;
  const int n = g & 15;
  const int d = (g >> 4) & 511;
  const int b = g >> 13;
  const float A  = -expf(Alog[d * 16 + n]);
  const float Dv = Dp[d];
  float h = 0.f;
  for (int i = 0; i < LL; ++i){
    const int t = rev ? (LL - 1 - i) : i;
    const size_t row = (size_t)(b * LL + t);
    const float dt = dtb[row * 512 + d];
    const float u  = xib[row * 512 + d];
    const float Bv = dblb[row * 48 + 16 + n];
    const float Cv = dblb[row * 48 + 32 + n];
    h = h * expf(dt * A) + dt * Bv * u;
    float p = h * Cv;
    p += __shfl_xor(p, 1); p += __shfl_xor(p, 2);
    p += __shfl_xor(p, 4); p += __shfl_xor(p, 8);
    if (n == 0){
      const float z = xzb[row * 1024 + 512 + d];
      ys[row * 512 + d] = (p + u * Dv) * (z / (1.f + expf(-z)));
    }
  }
}

// Flash attention. Block = (qtile of 64, head, batch), 256 threads.
// thread = (q_local = tid/4, dim group g = tid%4 -> dims g*16..g*16+15).
__global__ __launch_bounds__(256) void attn_kernel(
    const float* __restrict__ qkv, float* __restrict__ outp)
{
  const int qt = blockIdx.x, hh = blockIdx.y, b = blockIdx.z;
  const int tid = threadIdx.x;
  const int ql = tid >> 2, g = tid & 3;
  const int qrow = qt * 64 + ql;
  float qreg[16], o[16] = {};
  const size_t qbase = ((size_t)(b * LL) + qrow) * 768 + hh * 64 + g * 16;
  #pragma unroll
  for (int i = 0; i < 16; ++i) qreg[i] = qkv[qbase + i];
  float mrun = -INFINITY, lrun = 0.f;
  __shared__ float sK[64][64];
  __shared__ float sV[64][64];
  for (int kt = 0; kt < LL; kt += 64){
    __syncthreads();
    for (int idx = tid; idx < 4096; idx += 256){
      const int j = idx >> 6, c = idx & 63;
      const size_t kb = ((size_t)(b * LL) + kt + j) * 768 + hh * 64 + c;
      sK[j][c] = qkv[kb + 256];
      sV[j][c] = qkv[kb + 512];
    }
    __syncthreads();
    for (int j = 0; j < 64; ++j){
      float s = 0.f;
      #pragma unroll
      for (int i = 0; i < 16; ++i) s = fmaf(qreg[i], sK[j][g * 16 + i], s);
      s += __shfl_xor(s, 1); s += __shfl_xor(s, 2);
      s *= 0.125f;  // 1/sqrt(64)
      const float mn = fmaxf(mrun, s);
      const float alpha = expf(mrun - mn);
      const float p = expf(s - mn);
      lrun = lrun * alpha + p;
      #pragma unroll
      for (int i = 0; i < 16; ++i) o[i] = fmaf(o[i], alpha, p * sV[j][g * 16 + i]);
      mrun = mn;
    }
  }
  const float invl = 1.f / lrun;
  const size_t ob = ((size_t)(b * LL) + qrow) * DD + hh * 64 + g * 16;
  #pragma unroll
  for (int i = 0; i < 16; ++i) outp[ob + i] = o[i] * invl;
}

extern "C" void kernel_launch(void* const* d_in, const int* in_sizes, int n_in,
                              void* d_out, int out_size, void* d_ws, size_t ws_size,
                              hipStream_t stream)
{
  // setup_inputs() dict order:
  // 0 x | 1..9 mf_{Win,convw,convb,Wx,Wdt,bdt,Alog,D,Wout} | 10..18 mb_* |
  // 19..24 n1w,n1b,n2w,n2b,n3w,n3b | 25 Wqkv 26 bqkv 27 Wo 28 bo |
  // 29 fc1w 30 fc1b 31 fc2w 32 fc2b

  int* flag  = (int*)d_ws;
  float* wts = (float*)d_ws + 16;

  // weight offsets (element counts are dtype-independent)
  Srcs srcs;
  unsigned acc = 0;
  for (int i = 1; i <= 32; ++i){
    srcs.p[i - 1] = d_in[i];
    srcs.off[i - 1] = acc;
    acc += (unsigned)in_sizes[i];
  }
  srcs.off[32] = acc;
  const unsigned wtotal = acc;
  const size_t wpad = (size_t)((wtotal + 63u) & ~63u);

  float* xf    = wts   + wpad;         // 2,097,152  residual accumulator (fp32)
  float* hbuf  = xf    + 2097152;      // 2,097,152  LN output
  float* xzbuf = hbuf  + 2097152;      // 8,388,608  xz / qkv / fc1-out
  float* xibuf = xzbuf + 8388608;      // 4,194,304  conv+silu out (ys aliases this)
  float* dtbuf = xibuf + 4194304;      // 4,194,304  softplus(dt)
  float* dblbuf= dtbuf + 4194304;      //   393,216  x-proj (48 wide)
  float* ysbuf = xibuf;                // alias: scan reads u then writes ys same addr

  // fp32 weight pointers into wts
  auto wp = [&](int i){ return wts + srcs.off[i - 1]; };

  // --- dtype probe + weight conversion ---
  hipLaunchKernelGGL(probe_kernel, dim3(1), dim3(64), 0, stream,
      (const unsigned*)d_in[7], flag);
  hipLaunchKernelGGL(cvt_all_kernel, dim3((wtotal + 255) / 256), dim3(256), 0, stream,
      srcs, wts, flag, wtotal);
  hipLaunchKernelGGL(cvt_x_kernel, dim3(MTOT * DD / 256), dim3(256), 0, stream,
      d_in[0], xf, flag, (unsigned)(MTOT * DD));

  auto gemm = [&](const float* A, int lda, int iw, int ib,
                  float* C, float* resid, void* ob,
                  int N, int K, int mode){
    dim3 grid((N + 63) / 64, MTOT / 64);
    hipLaunchKernelGGL(gemm_kernel, grid, dim3(256), 0, stream,
        A, lda, wp(iw), ib >= 0 ? wp(ib) : nullptr, C, resid, ob, flag, N, K, mode);
  };

  // LN1: xf -> hbuf
  hipLaunchKernelGGL(ln_kernel, dim3(MTOT), dim3(256), 0, stream,
      xf, wp(19), wp(20), hbuf);

  // Bidirectional Mamba (sequential over directions, shared buffers)
  for (int dir = 0; dir < 2; ++dir){
    const int o = dir ? 10 : 1;
    // xz = h @ Win.T  [8192,1024]
    gemm(hbuf, DD, o + 0, -1, xzbuf, nullptr, nullptr, 1024, DD, M_PLAIN);
    // conv + bias + silu -> xi [8192,512]
    hipLaunchKernelGGL(conv_silu_kernel, dim3(MTOT * DINNER / 256), dim3(256), 0, stream,
        xzbuf, wp(o + 1), wp(o + 2), xibuf, dir);
    // dbl = xi @ Wx.T  [8192,48]
    gemm(xibuf, DINNER, o + 3, -1, dblbuf, nullptr, nullptr, 48, DINNER, M_PLAIN);
    // dt = softplus(dbl[:,:16] @ Wdt.T + bdt)  [8192,512]
    gemm(dblbuf, 48, o + 4, o + 5, dtbuf, nullptr, nullptr, DINNER, 16, M_SOFTPLUS);
    // selective scan -> ys (incl. skip D and silu(z) gate)
    hipLaunchKernelGGL(scan_kernel, dim3(128), dim3(256), 0, stream,
        dtbuf, xibuf, dblbuf, xzbuf, wp(o + 6), wp(o + 7), ysbuf, dir);
    // xf += ys @ Wout.T
    gemm(ysbuf, DINNER, o + 8, -1, nullptr, xf, nullptr, DD, DINNER, M_RESID);
  }

  // Attention
  hipLaunchKernelGGL(ln_kernel, dim3(MTOT), dim3(256), 0, stream,
      xf, wp(21), wp(22), hbuf);
  gemm(hbuf, DD, 25, 26, xzbuf, nullptr, nullptr, 768, DD, M_BIAS);   // qkv
  hipLaunchKernelGGL(attn_kernel, dim3(LL / 64, 4, 4), dim3(256), 0, stream,
      xzbuf, ysbuf);
  gemm(ysbuf, DD, 27, 28, nullptr, xf, nullptr, DD, DD, M_RESID);     // xf += o@Wo.T+bo

  // MLP
  hipLaunchKernelGGL(ln_kernel, dim3(MTOT), dim3(256), 0, stream,
      xf, wp(23), wp(24), hbuf);
  gemm(hbuf, DD, 29, 30, xzbuf, nullptr, nullptr, 1024, DD, M_GELU);  // gelu(fc1)
  gemm(xzbuf, 1024, 31, 32, nullptr, xf, d_out, DD, 1024, M_FINAL);   // out
}

// Round 3
// 1535.459 us; speedup vs baseline: 3.0433x; 3.0433x over previous
//
#include <hip/hip_runtime.h>
#include <hip/hip_bf16.h>
#include <math.h>

// Problem constants
#define LL 2048
#define DD 256
#define MTOT 8192       // B*L
#define DINNER 512
#define CT 128          // scan chunk length
#define NC 16           // chunks per sequence (CT*NC == LL)

__device__ __forceinline__ float us2f(unsigned short u){
  return __uint_as_float(((unsigned)u) << 16);
}

// ---- dtype probe: mf_Alog[0][0]=log(1)=0, [0][1]=log(2)!=0.
// fp32 word0 == 0x00000000 ; bf16 word0 == 0x3F310000  => word0!=0 <=> bf16
__global__ void probe_kernel(const unsigned* __restrict__ alog, int* __restrict__ flag){
  if (threadIdx.x == 0 && blockIdx.x == 0) *flag = (alog[0] != 0u) ? 1 : 0;
}

struct Srcs { const void* p[32]; unsigned off[33]; };

// Convert all 32 weight tensors (inputs 1..32) into packed fp32 at dst.
__global__ __launch_bounds__(256) void cvt_all_kernel(Srcs s, float* __restrict__ dst,
                                                      const int* __restrict__ flag,
                                                      unsigned total){
  unsigned i = blockIdx.x * 256u + threadIdx.x;
  if (i >= total) return;
  int k = 31;
  while (s.off[k] > i) --k;
  unsigned j = i - s.off[k];
  if (*flag) dst[i] = us2f(((const unsigned short*)s.p[k])[j]);
  else       dst[i] = ((const float*)s.p[k])[j];
}

// Convert x (input 0) to fp32 residual buffer.
__global__ __launch_bounds__(256) void cvt_x_kernel(const void* __restrict__ src,
                                                    float* __restrict__ dst,
                                                    const int* __restrict__ flag, unsigned n){
  unsigned i = blockIdx.x * 256u + threadIdx.x;
  if (i >= n) return;
  if (*flag) dst[i] = us2f(((const unsigned short*)src)[i]);
  else       dst[i] = ((const float*)src)[i];
}

enum { M_PLAIN=0, M_BIAS=1, M_SOFTPLUS=2, M_GELU=3, M_RESID=4, M_FINAL=5 };

// C[M,N] = epilogue( A[M,K](fp32,row,lda) * W[N,K](fp32,row)^T + bias )
// 64x64 tile, 256 threads, 4x4 microtile, BK=16.
__global__ __launch_bounds__(256) void gemm_kernel(
    const float* __restrict__ A, int lda,
    const float* __restrict__ W,
    const float* __restrict__ bias,
    float* __restrict__ C,
    float* __restrict__ resid,
    void* __restrict__ outb,
    const int* __restrict__ flag,
    int N, int K, int mode)
{
  __shared__ float sA[16][64];
  __shared__ float sB[16][64];
  const int tid = threadIdx.x;
  const int m0 = blockIdx.y << 6, n0 = blockIdx.x << 6;
  const int lr = tid >> 2, kq = tid & 3;   // loader: row-in-tile, k-quad
  const int tm = tid & 15, tn = tid >> 4;  // compute: 4x4 microtile coords
  const int wrow = n0 + lr;
  float acc[4][4] = {};
  for (int k0 = 0; k0 < K; k0 += 16){
    float4 av = *(const float4*)(A + (size_t)(m0 + lr) * lda + k0 + (kq << 2));
    float4 bv = make_float4(0.f, 0.f, 0.f, 0.f);
    if (wrow < N)
      bv = *(const float4*)(W + (size_t)wrow * K + k0 + (kq << 2));
    __syncthreads();
    const int kb = kq << 2;
    sA[kb+0][lr] = av.x; sA[kb+1][lr] = av.y; sA[kb+2][lr] = av.z; sA[kb+3][lr] = av.w;
    sB[kb+0][lr] = bv.x; sB[kb+1][lr] = bv.y; sB[kb+2][lr] = bv.z; sB[kb+3][lr] = bv.w;
    __syncthreads();
    #pragma unroll
    for (int k = 0; k < 16; ++k){
      float4 a4 = *(const float4*)&sA[k][tm << 2];
      float4 b4 = *(const float4*)&sB[k][tn << 2];
      float a[4] = {a4.x, a4.y, a4.z, a4.w};
      float b[4] = {b4.x, b4.y, b4.z, b4.w};
      #pragma unroll
      for (int i = 0; i < 4; ++i)
        #pragma unroll
        for (int j = 0; j < 4; ++j)
          acc[i][j] = fmaf(a[i], b[j], acc[i][j]);
    }
  }
  const int nc = n0 + (tn << 2);
  if (nc >= N) return;   // all N are multiples of 4; per-thread all-or-nothing
  float b4v[4] = {0.f, 0.f, 0.f, 0.f};
  if (bias){
    #pragma unroll
    for (int j = 0; j < 4; ++j) b4v[j] = bias[nc + j];
  }
  #pragma unroll
  for (int i = 0; i < 4; ++i){
    const int m = m0 + (tm << 2) + i;
    const size_t off = (size_t)m * N + nc;
    float r[4];
    #pragma unroll
    for (int j = 0; j < 4; ++j) r[j] = acc[i][j] + b4v[j];
    if (mode == M_SOFTPLUS){
      #pragma unroll
      for (int j = 0; j < 4; ++j) r[j] = (r[j] > 20.f) ? r[j] : log1pf(expf(r[j]));
      *(float4*)(C + off) = make_float4(r[0], r[1], r[2], r[3]);
    } else if (mode == M_GELU){
      #pragma unroll
      for (int j = 0; j < 4; ++j) r[j] = 0.5f * r[j] * (1.f + erff(r[j] * 0.70710678118f));
      *(float4*)(C + off) = make_float4(r[0], r[1], r[2], r[3]);
    } else if (mode == M_RESID){
      #pragma unroll
      for (int j = 0; j < 4; ++j) resid[off + j] += r[j];
    } else if (mode == M_FINAL){
      if (*flag){
        #pragma unroll
        for (int j = 0; j < 4; ++j)
          ((__hip_bfloat16*)outb)[off + j] = __float2bfloat16(resid[off + j] + r[j]);
      } else {
        #pragma unroll
        for (int j = 0; j < 4; ++j)
          ((float*)outb)[off + j] = resid[off + j] + r[j];
      }
    } else { // PLAIN / BIAS
      *(float4*)(C + off) = make_float4(r[0], r[1], r[2], r[3]);
    }
  }
}

// LayerNorm over D=256 (fp32 in, fp32 out). One block per row, thread = channel.
__global__ __launch_bounds__(256) void ln_kernel(
    const float* __restrict__ xin,
    const float* __restrict__ w, const float* __restrict__ b,
    float* __restrict__ hout)
{
  const int row = blockIdx.x, tid = threadIdx.x;
  const size_t off = (size_t)row * DD + tid;
  float v = xin[off];
  float s = v, s2 = v * v;
  #pragma unroll
  for (int o = 32; o; o >>= 1){ s += __shfl_xor(s, o); s2 += __shfl_xor(s2, o); }
  __shared__ float ls[4], ls2[4];
  if ((tid & 63) == 0){ ls[tid >> 6] = s; ls2[tid >> 6] = s2; }
  __syncthreads();
  s  = ls[0] + ls[1] + ls[2] + ls[3];
  s2 = ls2[0] + ls2[1] + ls2[2] + ls2[3];
  const float mu  = s * (1.f / DD);
  const float var = s2 * (1.f / DD) - mu * mu;
  const float inv = rsqrtf(var + 1e-5f);
  hout[off] = (v - mu) * inv * w[tid] + b[tid];
}

// Depthwise causal conv (D_CONV=4) + bias + SiLU.
// rev=0: y[t] = sum_k w[k]*x[t-3+k]; rev=1 (flip-conv-flip folded):
// y[t] = sum_j w[3-j]*x[t+j].  Input = xz[...,0:512] (row stride 1024).
__global__ __launch_bounds__(256) void conv_silu_kernel(
    const float* __restrict__ xz, const float* __restrict__ convw,
    const float* __restrict__ convb, float* __restrict__ xi, int rev)
{
  const int idx = blockIdx.x * 256 + threadIdx.x;   // (b*2048+t)*512 + c
  const int c = idx & 511;
  const int t = (idx >> 9) & 2047;
  const int b = idx >> 20;
  float acc = convb[c];
  if (!rev){
    #pragma unroll
    for (int k = 0; k < 4; ++k){
      int tt = t - 3 + k;
      if (tt >= 0) acc += convw[c*4 + k] * xz[((size_t)(b*2048 + tt))*1024 + c];
    }
  } else {
    #pragma unroll
    for (int j = 0; j < 4; ++j){
      int tt = t + j;
      if (tt < 2048) acc += convw[c*4 + 3 - j] * xz[((size_t)(b*2048 + tt))*1024 + c];
    }
  }
  xi[idx] = acc / (1.f + __expf(-acc));
}

// ---------------- Chunked selective scan ----------------
// Linear recurrence h[i] = a[i]*h[i-1] + b[i] over scan step i (t = rev? L-1-i : i).
// Split into NC chunks of CT. Pass1: per (b,d,n,chunk) compute decay product and
// chunk-local h_end (h0=0). Pass2: serial combine over chunks -> h_in per chunk.
// Pass3: recompute chunk scan seeded with h_in, emit gated output.
// Thread map (pass1/3): block = (b, c, dg); tid = n + 16*dd; d = dg*16+dd.
// chunk-state layout: [( (b*512+d)*16 + n )*NC + c]

__global__ __launch_bounds__(256) void scan_part1_kernel(
    const float* __restrict__ dtb, const float* __restrict__ xib,
    const float* __restrict__ dblb, const float* __restrict__ Alog,
    float* __restrict__ aprod, float* __restrict__ hend, int rev)
{
  const int bx = blockIdx.x;
  const int dg = bx & 31, c = (bx >> 5) & (NC - 1), b = bx >> 9;
  const int n = threadIdx.x & 15, dd = threadIdx.x >> 4;
  const int d = dg * 16 + dd;
  const float A = -__expf(Alog[d * 16 + n]);
  float ap = 1.f, h = 0.f;
  const int i0 = c * CT;
  for (int ii = 0; ii < CT; ++ii){
    const int i = i0 + ii;
    const int t = rev ? (LL - 1 - i) : i;
    const size_t row = (size_t)(b * LL + t);
    const float dt = dtb[row * 512 + d];
    const float u  = xib[row * 512 + d];
    const float Bv = dblb[row * 48 + 16 + n];
    const float e  = __expf(dt * A);
    h = h * e + dt * Bv * u;
    ap *= e;
  }
  const size_t idx = ((size_t)((b * 512 + d) * 16 + n)) * NC + c;
  aprod[idx] = ap;
  hend[idx]  = h;
}

// 32768 threads: one per (b,d,n). Serial combine over NC chunks.
__global__ __launch_bounds__(256) void scan_combine_kernel(
    const float* __restrict__ aprod, const float* __restrict__ hend,
    float* __restrict__ hin)
{
  const size_t g = (size_t)blockIdx.x * 256 + threadIdx.x;
  const size_t base = g * NC;
  float h = 0.f;
  #pragma unroll
  for (int c = 0; c < NC; ++c){
    hin[base + c] = h;
    h = aprod[base + c] * h + hend[base + c];
  }
}

__global__ __launch_bounds__(256) void scan_part2_kernel(
    const float* __restrict__ dtb, const float* __restrict__ xib,
    const float* __restrict__ dblb, const float* __restrict__ xzb,
    const float* __restrict__ Alog, const float* __restrict__ Dp,
    const float* __restrict__ hin, float* __restrict__ ys, int rev)
{
  const int bx = blockIdx.x;
  const int dg = bx & 31, c = (bx >> 5) & (NC - 1), b = bx >> 9;
  const int n = threadIdx.x & 15, dd = threadIdx.x >> 4;
  const int d = dg * 16 + dd;
  const float A  = -__expf(Alog[d * 16 + n]);
  const float Dv = Dp[d];
  float h = hin[((size_t)((b * 512 + d) * 16 + n)) * NC + c];
  const int i0 = c * CT;
  for (int ii = 0; ii < CT; ++ii){
    const int i = i0 + ii;
    const int t = rev ? (LL - 1 - i) : i;
    const size_t row = (size_t)(b * LL + t);
    const float dt = dtb[row * 512 + d];
    const float u  = xib[row * 512 + d];
    const float Bv = dblb[row * 48 + 16 + n];
    const float Cv = dblb[row * 48 + 32 + n];
    const float e  = __expf(dt * A);
    h = h * e + dt * Bv * u;
    float p = h * Cv;
    p += __shfl_xor(p, 1); p += __shfl_xor(p, 2);
    p += __shfl_xor(p, 4); p += __shfl_xor(p, 8);
    if (n == 0){
      const float z = xzb[row * 1024 + 512 + d];
      ys[row * 512 + d] = (p + u * Dv) * (z / (1.f + __expf(-z)));
    }
  }
}

// Flash attention. Block = (qtile of 64, head, batch), 256 threads.
// thread = (q_local = tid/4, dim group g = tid%4 -> dims g*16..g*16+15).
__global__ __launch_bounds__(256) void attn_kernel(
    const float* __restrict__ qkv, float* __restrict__ outp)
{
  const int qt = blockIdx.x, hh = blockIdx.y, b = blockIdx.z;
  const int tid = threadIdx.x;
  const int ql = tid >> 2, g = tid & 3;
  const int qrow = qt * 64 + ql;
  float qreg[16], o[16] = {};
  const size_t qbase = ((size_t)(b * LL) + qrow) * 768 + hh * 64 + g * 16;
  #pragma unroll
  for (int i = 0; i < 16; ++i) qreg[i] = qkv[qbase + i];
  float mrun = -INFINITY, lrun = 0.f;
  __shared__ float sK[64][64];
  __shared__ float sV[64][64];
  for (int kt = 0; kt < LL; kt += 64){
    __syncthreads();
    for (int idx = tid; idx < 4096; idx += 256){
      const int j = idx >> 6, c = idx & 63;
      const size_t kb = ((size_t)(b * LL) + kt + j) * 768 + hh * 64 + c;
      sK[j][c] = qkv[kb + 256];
      sV[j][c] = qkv[kb + 512];
    }
    __syncthreads();
    for (int j = 0; j < 64; ++j){
      float s = 0.f;
      #pragma unroll
      for (int i = 0; i < 16; ++i) s = fmaf(qreg[i], sK[j][g * 16 + i], s);
      s += __shfl_xor(s, 1); s += __shfl_xor(s, 2);
      s *= 0.125f;  // 1/sqrt(64)
      const float mn = fmaxf(mrun, s);
      const float alpha = __expf(mrun - mn);
      const float p = __expf(s - mn);
      lrun = lrun * alpha + p;
      #pragma unroll
      for (int i = 0; i < 16; ++i) o[i] = fmaf(o[i], alpha, p * sV[j][g * 16 + i]);
      mrun = mn;
    }
  }
  const float invl = 1.f / lrun;
  const size_t ob = ((size_t)(b * LL) + qrow) * DD + hh * 64 + g * 16;
  #pragma unroll
  for (int i = 0; i < 16; ++i) outp[ob + i] = o[i] * invl;
}

extern "C" void kernel_launch(void* const* d_in, const int* in_sizes, int n_in,
                              void* d_out, int out_size, void* d_ws, size_t ws_size,
                              hipStream_t stream)
{
  // setup_inputs() dict order:
  // 0 x | 1..9 mf_{Win,convw,convb,Wx,Wdt,bdt,Alog,D,Wout} | 10..18 mb_* |
  // 19..24 n1w,n1b,n2w,n2b,n3w,n3b | 25 Wqkv 26 bqkv 27 Wo 28 bo |
  // 29 fc1w 30 fc1b 31 fc2w 32 fc2b

  int* flag  = (int*)d_ws;
  float* wts = (float*)d_ws + 16;

  // weight offsets (element counts are dtype-independent)
  Srcs srcs;
  unsigned acc = 0;
  for (int i = 1; i <= 32; ++i){
    srcs.p[i - 1] = d_in[i];
    srcs.off[i - 1] = acc;
    acc += (unsigned)in_sizes[i];
  }
  srcs.off[32] = acc;
  const unsigned wtotal = acc;
  const size_t wpad = (size_t)((wtotal + 63u) & ~63u);

  float* xf    = wts   + wpad;         // 2,097,152  residual accumulator (fp32)
  float* hbuf  = xf    + 2097152;      // 2,097,152  LN output
  float* xzbuf = hbuf  + 2097152;      // 8,388,608  xz / qkv / fc1-out
  float* xibuf = xzbuf + 8388608;      // 4,194,304  conv+silu out (ys aliases this)
  float* dtbuf = xibuf + 4194304;      // 4,194,304  softplus(dt)
  float* dblbuf= dtbuf + 4194304;      //   393,216  x-proj (48 wide)
  float* aprod = dblbuf+ 393216;       //   524,288  chunk decay products
  float* hend  = aprod + 524288;       //   524,288  chunk-local h_end
  float* hinb  = hend  + 524288;       //   524,288  chunk incoming state
  float* ysbuf = xibuf;                // alias: scan reads u then writes ys same addr

  // fp32 weight pointers into wts
  auto wp = [&](int i){ return wts + srcs.off[i - 1]; };

  // --- dtype probe + weight conversion ---
  hipLaunchKernelGGL(probe_kernel, dim3(1), dim3(64), 0, stream,
      (const unsigned*)d_in[7], flag);
  hipLaunchKernelGGL(cvt_all_kernel, dim3((wtotal + 255) / 256), dim3(256), 0, stream,
      srcs, wts, flag, wtotal);
  hipLaunchKernelGGL(cvt_x_kernel, dim3(MTOT * DD / 256), dim3(256), 0, stream,
      d_in[0], xf, flag, (unsigned)(MTOT * DD));

  auto gemm = [&](const float* A, int lda, int iw, int ib,
                  float* C, float* resid, void* ob,
                  int N, int K, int mode){
    dim3 grid((N + 63) / 64, MTOT / 64);
    hipLaunchKernelGGL(gemm_kernel, grid, dim3(256), 0, stream,
        A, lda, wp(iw), ib >= 0 ? wp(ib) : nullptr, C, resid, ob, flag, N, K, mode);
  };

  // LN1: xf -> hbuf
  hipLaunchKernelGGL(ln_kernel, dim3(MTOT), dim3(256), 0, stream,
      xf, wp(19), wp(20), hbuf);

  // Bidirectional Mamba (sequential over directions, shared buffers)
  for (int dir = 0; dir < 2; ++dir){
    const int o = dir ? 10 : 1;
    // xz = h @ Win.T  [8192,1024]
    gemm(hbuf, DD, o + 0, -1, xzbuf, nullptr, nullptr, 1024, DD, M_PLAIN);
    // conv + bias + silu -> xi [8192,512]
    hipLaunchKernelGGL(conv_silu_kernel, dim3(MTOT * DINNER / 256), dim3(256), 0, stream,
        xzbuf, wp(o + 1), wp(o + 2), xibuf, dir);
    // dbl = xi @ Wx.T  [8192,48]
    gemm(xibuf, DINNER, o + 3, -1, dblbuf, nullptr, nullptr, 48, DINNER, M_PLAIN);
    // dt = softplus(dbl[:,:16] @ Wdt.T + bdt)  [8192,512]
    gemm(dblbuf, 48, o + 4, o + 5, dtbuf, nullptr, nullptr, DINNER, 16, M_SOFTPLUS);
    // chunked selective scan -> ys
    hipLaunchKernelGGL(scan_part1_kernel, dim3(4 * NC * 32), dim3(256), 0, stream,
        dtbuf, xibuf, dblbuf, wp(o + 6), aprod, hend, dir);
    hipLaunchKernelGGL(scan_combine_kernel, dim3(128), dim3(256), 0, stream,
        aprod, hend, hinb);
    hipLaunchKernelGGL(scan_part2_kernel, dim3(4 * NC * 32), dim3(256), 0, stream,
        dtbuf, xibuf, dblbuf, xzbuf, wp(o + 6), wp(o + 7), hinb, ysbuf, dir);
    // xf += ys @ Wout.T
    gemm(ysbuf, DINNER, o + 8, -1, nullptr, xf, nullptr, DD, DINNER, M_RESID);
  }

  // Attention
  hipLaunchKernelGGL(ln_kernel, dim3(MTOT), dim3(256), 0, stream,
      xf, wp(21), wp(22), hbuf);
  gemm(hbuf, DD, 25, 26, xzbuf, nullptr, nullptr, 768, DD, M_BIAS);   // qkv
  hipLaunchKernelGGL(attn_kernel, dim3(LL / 64, 4, 4), dim3(256), 0, stream,
      xzbuf, ysbuf);
  gemm(ysbuf, DD, 27, 28, nullptr, xf, nullptr, DD, DD, M_RESID);     // xf += o@Wo.T+bo

  // MLP
  hipLaunchKernelGGL(ln_kernel, dim3(MTOT), dim3(256), 0, stream,
      xf, wp(23), wp(24), hbuf);
  gemm(hbuf, DD, 29, 30, xzbuf, nullptr, nullptr, 1024, DD, M_GELU);  // gelu(fc1)
  gemm(xzbuf, 1024, 31, 32, nullptr, xf, d_out, DD, 1024, M_FINAL);   // out
}

// Round 4
// 1099.175 us; speedup vs baseline: 4.2512x; 1.3969x over previous
//
#include <hip/hip_runtime.h>
#include <hip/hip_bf16.h>
#include <math.h>

// Problem constants
#define LL 2048
#define DD 256
#define MTOT 8192       // B*L
#define DINNER 512
#define CT 128          // scan chunk length
#define NC 16           // chunks per sequence (CT*NC == LL)

__device__ __forceinline__ float us2f(unsigned short u){
  return __uint_as_float(((unsigned)u) << 16);
}
__device__ __forceinline__ unsigned short f2us(float f){
  __hip_bfloat16 h = __float2bfloat16(f);
  return *(unsigned short*)&h;
}

// ---- dtype probe: mf_Alog[0][0]=log(1)=0, [0][1]=log(2)!=0.
// fp32 word0 == 0x00000000 ; bf16 word0 == 0x3F310000  => word0!=0 <=> bf16
__global__ void probe_kernel(const unsigned* __restrict__ alog, int* __restrict__ flag){
  if (threadIdx.x == 0 && blockIdx.x == 0) *flag = (alog[0] != 0u) ? 1 : 0;
}

struct Srcs { const void* p[32]; unsigned off[33]; };

// Convert all 32 weight tensors (inputs 1..32) into packed fp32 at dst.
__global__ __launch_bounds__(256) void cvt_all_kernel(Srcs s, float* __restrict__ dst,
                                                      const int* __restrict__ flag,
                                                      unsigned total){
  unsigned i = blockIdx.x * 256u + threadIdx.x;
  if (i >= total) return;
  int k = 31;
  while (s.off[k] > i) --k;
  unsigned j = i - s.off[k];
  if (*flag) dst[i] = us2f(((const unsigned short*)s.p[k])[j]);
  else       dst[i] = ((const float*)s.p[k])[j];
}

// Convert x (input 0) to fp32 residual buffer.
__global__ __launch_bounds__(256) void cvt_x_kernel(const void* __restrict__ src,
                                                    float* __restrict__ dst,
                                                    const int* __restrict__ flag, unsigned n){
  unsigned i = blockIdx.x * 256u + threadIdx.x;
  if (i >= n) return;
  if (*flag) dst[i] = us2f(((const unsigned short*)src)[i]);
  else       dst[i] = ((const float*)src)[i];
}

enum { M_PLAIN=0, M_BIAS=1, M_SOFTPLUS=2, M_GELU=3, M_RESID=4, M_FINAL=5 };

// C[M,N] = epilogue( A[M,K](fp32,row,lda) * W[N,K](fp32,row)^T + bias )
// 64x64 tile, 256 threads, 4x4 microtile, BK=16.
__global__ __launch_bounds__(256) void gemm_kernel(
    const float* __restrict__ A, int lda,
    const float* __restrict__ W,
    const float* __restrict__ bias,
    float* __restrict__ C,
    float* __restrict__ resid,
    void* __restrict__ outb,
    const int* __restrict__ flag,
    int N, int K, int mode)
{
  __shared__ float sA[16][64];
  __shared__ float sB[16][64];
  const int tid = threadIdx.x;
  const int m0 = blockIdx.y << 6, n0 = blockIdx.x << 6;
  const int lr = tid >> 2, kq = tid & 3;   // loader: row-in-tile, k-quad
  const int tm = tid & 15, tn = tid >> 4;  // compute: 4x4 microtile coords
  const int wrow = n0 + lr;
  float acc[4][4] = {};
  for (int k0 = 0; k0 < K; k0 += 16){
    float4 av = *(const float4*)(A + (size_t)(m0 + lr) * lda + k0 + (kq << 2));
    float4 bv = make_float4(0.f, 0.f, 0.f, 0.f);
    if (wrow < N)
      bv = *(const float4*)(W + (size_t)wrow * K + k0 + (kq << 2));
    __syncthreads();
    const int kb = kq << 2;
    sA[kb+0][lr] = av.x; sA[kb+1][lr] = av.y; sA[kb+2][lr] = av.z; sA[kb+3][lr] = av.w;
    sB[kb+0][lr] = bv.x; sB[kb+1][lr] = bv.y; sB[kb+2][lr] = bv.z; sB[kb+3][lr] = bv.w;
    __syncthreads();
    #pragma unroll
    for (int k = 0; k < 16; ++k){
      float4 a4 = *(const float4*)&sA[k][tm << 2];
      float4 b4 = *(const float4*)&sB[k][tn << 2];
      float a[4] = {a4.x, a4.y, a4.z, a4.w};
      float b[4] = {b4.x, b4.y, b4.z, b4.w};
      #pragma unroll
      for (int i = 0; i < 4; ++i)
        #pragma unroll
        for (int j = 0; j < 4; ++j)
          acc[i][j] = fmaf(a[i], b[j], acc[i][j]);
    }
  }
  const int nc = n0 + (tn << 2);
  if (nc >= N) return;   // all N are multiples of 4; per-thread all-or-nothing
  float b4v[4] = {0.f, 0.f, 0.f, 0.f};
  if (bias){
    #pragma unroll
    for (int j = 0; j < 4; ++j) b4v[j] = bias[nc + j];
  }
  #pragma unroll
  for (int i = 0; i < 4; ++i){
    const int m = m0 + (tm << 2) + i;
    const size_t off = (size_t)m * N + nc;
    float r[4];
    #pragma unroll
    for (int j = 0; j < 4; ++j) r[j] = acc[i][j] + b4v[j];
    if (mode == M_SOFTPLUS){
      #pragma unroll
      for (int j = 0; j < 4; ++j) r[j] = (r[j] > 20.f) ? r[j] : log1pf(expf(r[j]));
      *(float4*)(C + off) = make_float4(r[0], r[1], r[2], r[3]);
    } else if (mode == M_GELU){
      #pragma unroll
      for (int j = 0; j < 4; ++j) r[j] = 0.5f * r[j] * (1.f + erff(r[j] * 0.70710678118f));
      *(float4*)(C + off) = make_float4(r[0], r[1], r[2], r[3]);
    } else if (mode == M_RESID){
      #pragma unroll
      for (int j = 0; j < 4; ++j) resid[off + j] += r[j];
    } else if (mode == M_FINAL){
      if (*flag){
        #pragma unroll
        for (int j = 0; j < 4; ++j)
          ((__hip_bfloat16*)outb)[off + j] = __float2bfloat16(resid[off + j] + r[j]);
      } else {
        #pragma unroll
        for (int j = 0; j < 4; ++j)
          ((float*)outb)[off + j] = resid[off + j] + r[j];
      }
    } else { // PLAIN / BIAS
      *(float4*)(C + off) = make_float4(r[0], r[1], r[2], r[3]);
    }
  }
}

// LayerNorm over D=256 (fp32 in, fp32 out). One block per row, thread = channel.
__global__ __launch_bounds__(256) void ln_kernel(
    const float* __restrict__ xin,
    const float* __restrict__ w, const float* __restrict__ b,
    float* __restrict__ hout)
{
  const int row = blockIdx.x, tid = threadIdx.x;
  const size_t off = (size_t)row * DD + tid;
  float v = xin[off];
  float s = v, s2 = v * v;
  #pragma unroll
  for (int o = 32; o; o >>= 1){ s += __shfl_xor(s, o); s2 += __shfl_xor(s2, o); }
  __shared__ float ls[4], ls2[4];
  if ((tid & 63) == 0){ ls[tid >> 6] = s; ls2[tid >> 6] = s2; }
  __syncthreads();
  s  = ls[0] + ls[1] + ls[2] + ls[3];
  s2 = ls2[0] + ls2[1] + ls2[2] + ls2[3];
  const float mu  = s * (1.f / DD);
  const float var = s2 * (1.f / DD) - mu * mu;
  const float inv = rsqrtf(var + 1e-5f);
  hout[off] = (v - mu) * inv * w[tid] + b[tid];
}

// Depthwise causal conv (D_CONV=4) + bias + SiLU.
__global__ __launch_bounds__(256) void conv_silu_kernel(
    const float* __restrict__ xz, const float* __restrict__ convw,
    const float* __restrict__ convb, float* __restrict__ xi, int rev)
{
  const int idx = blockIdx.x * 256 + threadIdx.x;   // (b*2048+t)*512 + c
  const int c = idx & 511;
  const int t = (idx >> 9) & 2047;
  const int b = idx >> 20;
  float acc = convb[c];
  if (!rev){
    #pragma unroll
    for (int k = 0; k < 4; ++k){
      int tt = t - 3 + k;
      if (tt >= 0) acc += convw[c*4 + k] * xz[((size_t)(b*2048 + tt))*1024 + c];
    }
  } else {
    #pragma unroll
    for (int j = 0; j < 4; ++j){
      int tt = t + j;
      if (tt < 2048) acc += convw[c*4 + 3 - j] * xz[((size_t)(b*2048 + tt))*1024 + c];
    }
  }
  xi[idx] = acc / (1.f + __expf(-acc));
}

// ---------------- Chunked selective scan ----------------
__global__ __launch_bounds__(256) void scan_part1_kernel(
    const float* __restrict__ dtb, const float* __restrict__ xib,
    const float* __restrict__ dblb, const float* __restrict__ Alog,
    float* __restrict__ aprod, float* __restrict__ hend, int rev)
{
  const int bx = blockIdx.x;
  const int dg = bx & 31, c = (bx >> 5) & (NC - 1), b = bx >> 9;
  const int n = threadIdx.x & 15, dd = threadIdx.x >> 4;
  const int d = dg * 16 + dd;
  const float A = -__expf(Alog[d * 16 + n]);
  float ap = 1.f, h = 0.f;
  const int i0 = c * CT;
  for (int ii = 0; ii < CT; ++ii){
    const int i = i0 + ii;
    const int t = rev ? (LL - 1 - i) : i;
    const size_t row = (size_t)(b * LL + t);
    const float dt = dtb[row * 512 + d];
    const float u  = xib[row * 512 + d];
    const float Bv = dblb[row * 48 + 16 + n];
    const float e  = __expf(dt * A);
    h = h * e + dt * Bv * u;
    ap *= e;
  }
  const size_t idx = ((size_t)((b * 512 + d) * 16 + n)) * NC + c;
  aprod[idx] = ap;
  hend[idx]  = h;
}

__global__ __launch_bounds__(256) void scan_combine_kernel(
    const float* __restrict__ aprod, const float* __restrict__ hend,
    float* __restrict__ hin)
{
  const size_t g = (size_t)blockIdx.x * 256 + threadIdx.x;
  const size_t base = g * NC;
  float h = 0.f;
  #pragma unroll
  for (int c = 0; c < NC; ++c){
    hin[base + c] = h;
    h = aprod[base + c] * h + hend[base + c];
  }
}

__global__ __launch_bounds__(256) void scan_part2_kernel(
    const float* __restrict__ dtb, const float* __restrict__ xib,
    const float* __restrict__ dblb, const float* __restrict__ xzb,
    const float* __restrict__ Alog, const float* __restrict__ Dp,
    const float* __restrict__ hin, float* __restrict__ ys, int rev)
{
  const int bx = blockIdx.x;
  const int dg = bx & 31, c = (bx >> 5) & (NC - 1), b = bx >> 9;
  const int n = threadIdx.x & 15, dd = threadIdx.x >> 4;
  const int d = dg * 16 + dd;
  const float A  = -__expf(Alog[d * 16 + n]);
  const float Dv = Dp[d];
  float h = hin[((size_t)((b * 512 + d) * 16 + n)) * NC + c];
  const int i0 = c * CT;
  for (int ii = 0; ii < CT; ++ii){
    const int i = i0 + ii;
    const int t = rev ? (LL - 1 - i) : i;
    const size_t row = (size_t)(b * LL + t);
    const float dt = dtb[row * 512 + d];
    const float u  = xib[row * 512 + d];
    const float Bv = dblb[row * 48 + 16 + n];
    const float Cv = dblb[row * 48 + 32 + n];
    const float e  = __expf(dt * A);
    h = h * e + dt * Bv * u;
    float p = h * Cv;
    p += __shfl_xor(p, 1); p += __shfl_xor(p, 2);
    p += __shfl_xor(p, 4); p += __shfl_xor(p, 8);
    if (n == 0){
      const float z = xzb[row * 1024 + 512 + d];
      ys[row * 512 + d] = (p + u * Dv) * (z / (1.f + __expf(-z)));
    }
  }
}

// ---------------- MFMA flash attention ----------------
// qkv fp32 [8192,768] -> Qb,Kb bf16 [bh,2048,64] (cols 0..511)
__global__ __launch_bounds__(256) void qk_prep_kernel(
    const float* __restrict__ qkv,
    unsigned short* __restrict__ Qb, unsigned short* __restrict__ Kb)
{
  const unsigned g = blockIdx.x * 256u + threadIdx.x;   // 1,048,576 threads
  const int row = g >> 7;               // 0..8191
  const int col = (g & 127) << 2;       // 0..508
  float4 v = *(const float4*)(qkv + (size_t)row * 768 + col);
  const int b = row >> 11, l = row & 2047;
  const int hc = col & 255;
  const int h = hc >> 6, d = hc & 63;
  unsigned short* dst = (col < 256) ? Qb : Kb;
  dst += ((size_t)((b * 4 + h) * 2048 + l)) * 64 + d;
  ushort4 o;
  o.x = f2us(v.x); o.y = f2us(v.y); o.z = f2us(v.z); o.w = f2us(v.w);
  *(ushort4*)dst = o;
}

// qkv fp32 cols 512..767 -> Vt bf16 [bh,64,2048] (transposed via LDS tile)
__global__ __launch_bounds__(256) void v_prep_kernel(
    const float* __restrict__ qkv, unsigned short* __restrict__ Vt)
{
  const int kt = blockIdx.x;            // 0..31 (64-key tile)
  const int bh = blockIdx.y;            // 0..15
  const int b = bh >> 2, h = bh & 3;
  __shared__ float tile[64][68];
  #pragma unroll
  for (int rr = 0; rr < 4; ++rr){
    const int idx = (rr * 256 + threadIdx.x) * 4;
    const int key = idx >> 6, d = idx & 63;
    float4 v = *(const float4*)(qkv + ((size_t)(b * 2048 + kt * 64 + key)) * 768 + 512 + h * 64 + d);
    *(float4*)&tile[key][d] = v;
  }
  __syncthreads();
  #pragma unroll
  for (int rr = 0; rr < 8; ++rr){
    const int o2 = rr * 256 + threadIdx.x;    // 0..2047
    const int d = o2 >> 5, k2 = (o2 & 31) << 1;
    ushort2 u;
    u.x = f2us(tile[k2][d]);
    u.y = f2us(tile[k2 + 1][d]);
    *(ushort2*)(Vt + (size_t)bh * 131072 + (size_t)d * 2048 + kt * 64 + k2) = u;
  }
}

// Flash attention, bf16 MFMA 16x16x32. Block = 64 queries x (b,h); 4 waves x 16 q.
__global__ __launch_bounds__(256) void attn_mfma_kernel(
    const unsigned short* __restrict__ Qb, const unsigned short* __restrict__ Kb,
    const unsigned short* __restrict__ Vt, float* __restrict__ outp)
{
  using short8 = __attribute__((ext_vector_type(8))) short;
  using f32x4  = __attribute__((ext_vector_type(4))) float;
  __shared__ unsigned short sK[64][72];       // keys x dims (pad 72 -> 2-way only)
  __shared__ unsigned short sV[64][72];       // dims x keys
  __shared__ unsigned short sP[4][16][72];    // per-wave P: queries x keys
  const int tid = threadIdx.x;
  const int w = tid >> 6, lane = tid & 63, quad = lane >> 4, l16 = lane & 15;
  const int bh = blockIdx.y;
  const int q0 = blockIdx.x * 64;
  const size_t qkbase = (size_t)bh * 2048 * 64;

  const unsigned short* qp = Qb + qkbase + (size_t)(q0 + w * 16 + l16) * 64 + quad * 8;
  short8 qf0 = *(const short8*)qp;
  short8 qf1 = *(const short8*)(qp + 32);

  f32x4 o[4] = {{0,0,0,0},{0,0,0,0},{0,0,0,0},{0,0,0,0}};
  float mold[4] = {-INFINITY,-INFINITY,-INFINITY,-INFINITY};
  float lsum[4] = {0.f,0.f,0.f,0.f};

  for (int kt = 0; kt < LL; kt += 64){
    __syncthreads();
    #pragma unroll
    for (int r = 0; r < 2; ++r){
      const int idx = (r * 256 + tid) * 8;
      const int row = idx >> 6, c = idx & 63;
      *(short8*)&sK[row][c] = *(const short8*)(Kb + qkbase + (size_t)(kt + row) * 64 + c);
      *(short8*)&sV[row][c] = *(const short8*)(Vt + (size_t)bh * 131072 + (size_t)row * 2048 + kt + c);
    }
    __syncthreads();

    // QK^T: scores p[sub][r] for key col sub*16+l16, query row quad*4+r
    float p[4][4];
    #pragma unroll
    for (int sub = 0; sub < 4; ++sub){
      short8 bk0 = *(const short8*)&sK[sub * 16 + l16][quad * 8];
      short8 bk1 = *(const short8*)&sK[sub * 16 + l16][32 + quad * 8];
      f32x4 acc = {0,0,0,0};
      acc = __builtin_amdgcn_mfma_f32_16x16x32_bf16(qf0, bk0, acc, 0, 0, 0);
      acc = __builtin_amdgcn_mfma_f32_16x16x32_bf16(qf1, bk1, acc, 0, 0, 0);
      #pragma unroll
      for (int r = 0; r < 4; ++r) p[sub][r] = acc[r] * 0.125f;
    }
    // online softmax per query row
    #pragma unroll
    for (int r = 0; r < 4; ++r){
      float m = fmaxf(fmaxf(p[0][r], p[1][r]), fmaxf(p[2][r], p[3][r]));
      m = fmaxf(m, __shfl_xor(m, 1)); m = fmaxf(m, __shfl_xor(m, 2));
      m = fmaxf(m, __shfl_xor(m, 4)); m = fmaxf(m, __shfl_xor(m, 8));
      const float mnew = fmaxf(mold[r], m);
      const float alpha = __expf(mold[r] - mnew);
      mold[r] = mnew;
      float rs = 0.f;
      #pragma unroll
      for (int sub = 0; sub < 4; ++sub){ p[sub][r] = __expf(p[sub][r] - mnew); rs += p[sub][r]; }
      rs += __shfl_xor(rs, 1); rs += __shfl_xor(rs, 2);
      rs += __shfl_xor(rs, 4); rs += __shfl_xor(rs, 8);
      lsum[r] = lsum[r] * alpha + rs;
      #pragma unroll
      for (int nsub = 0; nsub < 4; ++nsub) o[nsub][r] *= alpha;
    }
    // P -> LDS (C-layout -> A-layout round trip), bf16
    #pragma unroll
    for (int sub = 0; sub < 4; ++sub)
      #pragma unroll
      for (int r = 0; r < 4; ++r)
        sP[w][quad * 4 + r][sub * 16 + l16] = f2us(p[sub][r]);
    // PV
    short8 pa0 = *(const short8*)&sP[w][l16][quad * 8];
    short8 pa1 = *(const short8*)&sP[w][l16][32 + quad * 8];
    #pragma unroll
    for (int nsub = 0; nsub < 4; ++nsub){
      short8 bv0 = *(const short8*)&sV[nsub * 16 + l16][quad * 8];
      short8 bv1 = *(const short8*)&sV[nsub * 16 + l16][32 + quad * 8];
      o[nsub] = __builtin_amdgcn_mfma_f32_16x16x32_bf16(pa0, bv0, o[nsub], 0, 0, 0);
      o[nsub] = __builtin_amdgcn_mfma_f32_16x16x32_bf16(pa1, bv1, o[nsub], 0, 0, 0);
    }
  }

  const int b = bh >> 2, h = bh & 3;
  #pragma unroll
  for (int r = 0; r < 4; ++r){
    const float invl = 1.f / lsum[r];
    const int q = q0 + w * 16 + quad * 4 + r;
    #pragma unroll
    for (int nsub = 0; nsub < 4; ++nsub)
      outp[((size_t)(b * 2048 + q)) * 256 + h * 64 + nsub * 16 + l16] = o[nsub][r] * invl;
  }
}

extern "C" void kernel_launch(void* const* d_in, const int* in_sizes, int n_in,
                              void* d_out, int out_size, void* d_ws, size_t ws_size,
                              hipStream_t stream)
{
  // setup_inputs() dict order:
  // 0 x | 1..9 mf_{Win,convw,convb,Wx,Wdt,bdt,Alog,D,Wout} | 10..18 mb_* |
  // 19..24 n1w,n1b,n2w,n2b,n3w,n3b | 25 Wqkv 26 bqkv 27 Wo 28 bo |
  // 29 fc1w 30 fc1b 31 fc2w 32 fc2b

  int* flag  = (int*)d_ws;
  float* wts = (float*)d_ws + 16;

  Srcs srcs;
  unsigned acc = 0;
  for (int i = 1; i <= 32; ++i){
    srcs.p[i - 1] = d_in[i];
    srcs.off[i - 1] = acc;
    acc += (unsigned)in_sizes[i];
  }
  srcs.off[32] = acc;
  const unsigned wtotal = acc;
  const size_t wpad = (size_t)((wtotal + 63u) & ~63u);

  float* xf    = wts   + wpad;         // 2,097,152  residual accumulator (fp32)
  float* hbuf  = xf    + 2097152;      // 2,097,152  LN output
  float* xzbuf = hbuf  + 2097152;      // 8,388,608  xz / qkv / fc1-out
  float* xibuf = xzbuf + 8388608;      // 4,194,304  conv+silu out (ys aliases this)
  float* dtbuf = xibuf + 4194304;      // 4,194,304  softplus(dt); free at attn time
  float* dblbuf= dtbuf + 4194304;      //   393,216  x-proj (48 wide)
  float* aprod = dblbuf+ 393216;       //   524,288  chunk decay products
  float* hend  = aprod + 524288;       //   524,288  chunk-local h_end
  float* hinb  = hend  + 524288;       //   524,288  chunk incoming state
  float* ysbuf = xibuf;                // alias
  // bf16 attention operands overlay dtbuf (3M floats needed of 4.19M)
  unsigned short* Qb = (unsigned short*)dtbuf;              // 2M bf16
  unsigned short* Kb = (unsigned short*)(dtbuf + 1048576);  // 2M bf16
  unsigned short* Vt = (unsigned short*)(dtbuf + 2097152);  // 2M bf16

  auto wp = [&](int i){ return wts + srcs.off[i - 1]; };

  hipLaunchKernelGGL(probe_kernel, dim3(1), dim3(64), 0, stream,
      (const unsigned*)d_in[7], flag);
  hipLaunchKernelGGL(cvt_all_kernel, dim3((wtotal + 255) / 256), dim3(256), 0, stream,
      srcs, wts, flag, wtotal);
  hipLaunchKernelGGL(cvt_x_kernel, dim3(MTOT * DD / 256), dim3(256), 0, stream,
      d_in[0], xf, flag, (unsigned)(MTOT * DD));

  auto gemm = [&](const float* A, int lda, int iw, int ib,
                  float* C, float* resid, void* ob,
                  int N, int K, int mode){
    dim3 grid((N + 63) / 64, MTOT / 64);
    hipLaunchKernelGGL(gemm_kernel, grid, dim3(256), 0, stream,
        A, lda, wp(iw), ib >= 0 ? wp(ib) : nullptr, C, resid, ob, flag, N, K, mode);
  };

  // LN1
  hipLaunchKernelGGL(ln_kernel, dim3(MTOT), dim3(256), 0, stream,
      xf, wp(19), wp(20), hbuf);

  // Bidirectional Mamba
  for (int dir = 0; dir < 2; ++dir){
    const int o = dir ? 10 : 1;
    gemm(hbuf, DD, o + 0, -1, xzbuf, nullptr, nullptr, 1024, DD, M_PLAIN);
    hipLaunchKernelGGL(conv_silu_kernel, dim3(MTOT * DINNER / 256), dim3(256), 0, stream,
        xzbuf, wp(o + 1), wp(o + 2), xibuf, dir);
    gemm(xibuf, DINNER, o + 3, -1, dblbuf, nullptr, nullptr, 48, DINNER, M_PLAIN);
    gemm(dblbuf, 48, o + 4, o + 5, dtbuf, nullptr, nullptr, DINNER, 16, M_SOFTPLUS);
    hipLaunchKernelGGL(scan_part1_kernel, dim3(4 * NC * 32), dim3(256), 0, stream,
        dtbuf, xibuf, dblbuf, wp(o + 6), aprod, hend, dir);
    hipLaunchKernelGGL(scan_combine_kernel, dim3(128), dim3(256), 0, stream,
        aprod, hend, hinb);
    hipLaunchKernelGGL(scan_part2_kernel, dim3(4 * NC * 32), dim3(256), 0, stream,
        dtbuf, xibuf, dblbuf, xzbuf, wp(o + 6), wp(o + 7), hinb, ysbuf, dir);
    gemm(ysbuf, DINNER, o + 8, -1, nullptr, xf, nullptr, DD, DINNER, M_RESID);
  }

  // Attention
  hipLaunchKernelGGL(ln_kernel, dim3(MTOT), dim3(256), 0, stream,
      xf, wp(21), wp(22), hbuf);
  gemm(hbuf, DD, 25, 26, xzbuf, nullptr, nullptr, 768, DD, M_BIAS);   // qkv fp32
  hipLaunchKernelGGL(qk_prep_kernel, dim3(4096), dim3(256), 0, stream,
      xzbuf, Qb, Kb);
  hipLaunchKernelGGL(v_prep_kernel, dim3(32, 16), dim3(256), 0, stream,
      xzbuf, Vt);
  hipLaunchKernelGGL(attn_mfma_kernel, dim3(32, 16), dim3(256), 0, stream,
      Qb, Kb, Vt, ysbuf);
  gemm(ysbuf, DD, 27, 28, nullptr, xf, nullptr, DD, DD, M_RESID);     // xf += o@Wo.T+bo

  // MLP
  hipLaunchKernelGGL(ln_kernel, dim3(MTOT), dim3(256), 0, stream,
      xf, wp(23), wp(24), hbuf);
  gemm(hbuf, DD, 29, 30, xzbuf, nullptr, nullptr, 1024, DD, M_GELU);
  gemm(xzbuf, 1024, 31, 32, nullptr, xf, d_out, DD, 1024, M_FINAL);
}

// Round 5
// 622.564 us; speedup vs baseline: 7.5057x; 1.7656x over previous
//
#include <hip/hip_runtime.h>
#include <hip/hip_bf16.h>
#include <math.h>

// Problem constants
#define LL 2048
#define DD 256
#define MTOT 8192       // B*L
#define DINNER 512
#define CT 32           // scan chunk length
#define NC 64           // chunks per sequence (CT*NC == LL)

typedef __attribute__((ext_vector_type(8))) short short8;
typedef __attribute__((ext_vector_type(4))) float f32x4;

__device__ __forceinline__ float us2f(unsigned short u){
  return __uint_as_float(((unsigned)u) << 16);
}
__device__ __forceinline__ unsigned short f2us(float f){
  __hip_bfloat16 h = __float2bfloat16(f);
  return *(unsigned short*)&h;
}

// ---- dtype probe: mf_Alog[0][0]=log(1)=0 -> fp32 word0==0; bf16 word0!=0
__global__ void probe_kernel(const unsigned* __restrict__ alog, int* __restrict__ flag){
  if (threadIdx.x == 0 && blockIdx.x == 0) *flag = (alog[0] != 0u) ? 1 : 0;
}

struct Srcs { const void* p[32]; unsigned off[33]; unsigned foff[32]; };

// Convert weights: bf16 copy of everything, fp32 copy of the subset with foff valid.
__global__ __launch_bounds__(256) void cvt_all_kernel(Srcs s, float* __restrict__ dst,
                                                      unsigned short* __restrict__ db,
                                                      const int* __restrict__ flag,
                                                      unsigned total){
  unsigned i = blockIdx.x * 256u + threadIdx.x;
  if (i >= total) return;
  int k = 31;
  while (s.off[k] > i) --k;
  unsigned j = i - s.off[k];
  float v;
  if (*flag) v = us2f(((const unsigned short*)s.p[k])[j]);
  else       v = ((const float*)s.p[k])[j];
  db[i] = f2us(v);
  if (s.foff[k] != 0xFFFFFFFFu) dst[s.foff[k] + j] = v;
}

__global__ __launch_bounds__(256) void cvt_x_kernel(const void* __restrict__ src,
                                                    float* __restrict__ dst,
                                                    const int* __restrict__ flag, unsigned n){
  unsigned i = blockIdx.x * 256u + threadIdx.x;
  if (i >= n) return;
  if (*flag) dst[i] = us2f(((const unsigned short*)src)[i]);
  else       dst[i] = ((const float*)src)[i];
}

// ---------------- small fp32 GEMM (dbl: N=48; dt: K=16) ----------------
// mode 0: plain fp32 C.  mode 1: softplus(v+bias) -> bf16 C.
__global__ __launch_bounds__(256) void gemm_small_kernel(
    const float* __restrict__ A, int lda,
    const float* __restrict__ W,
    const float* __restrict__ bias,
    void* __restrict__ C,
    int N, int K, int mode)
{
  __shared__ float sA[16][64];
  __shared__ float sB[16][64];
  const int tid = threadIdx.x;
  const int m0 = blockIdx.y << 6, n0 = blockIdx.x << 6;
  const int lr = tid >> 2, kq = tid & 3;
  const int tm = tid & 15, tn = tid >> 4;
  const int wrow = n0 + lr;
  float acc[4][4] = {};
  for (int k0 = 0; k0 < K; k0 += 16){
    float4 av = *(const float4*)(A + (size_t)(m0 + lr) * lda + k0 + (kq << 2));
    float4 bv = make_float4(0.f, 0.f, 0.f, 0.f);
    if (wrow < N)
      bv = *(const float4*)(W + (size_t)wrow * K + k0 + (kq << 2));
    __syncthreads();
    const int kb = kq << 2;
    sA[kb+0][lr] = av.x; sA[kb+1][lr] = av.y; sA[kb+2][lr] = av.z; sA[kb+3][lr] = av.w;
    sB[kb+0][lr] = bv.x; sB[kb+1][lr] = bv.y; sB[kb+2][lr] = bv.z; sB[kb+3][lr] = bv.w;
    __syncthreads();
    #pragma unroll
    for (int k = 0; k < 16; ++k){
      float4 a4 = *(const float4*)&sA[k][tm << 2];
      float4 b4 = *(const float4*)&sB[k][tn << 2];
      float a[4] = {a4.x, a4.y, a4.z, a4.w};
      float b[4] = {b4.x, b4.y, b4.z, b4.w};
      #pragma unroll
      for (int i = 0; i < 4; ++i)
        #pragma unroll
        for (int j = 0; j < 4; ++j)
          acc[i][j] = fmaf(a[i], b[j], acc[i][j]);
    }
  }
  const int nc = n0 + (tn << 2);
  if (nc >= N) return;
  float b4v[4] = {0.f, 0.f, 0.f, 0.f};
  if (bias){
    #pragma unroll
    for (int j = 0; j < 4; ++j) b4v[j] = bias[nc + j];
  }
  #pragma unroll
  for (int i = 0; i < 4; ++i){
    const int m = m0 + (tm << 2) + i;
    const size_t off = (size_t)m * N + nc;
    float r[4];
    #pragma unroll
    for (int j = 0; j < 4; ++j) r[j] = acc[i][j] + b4v[j];
    if (mode == 0){
      *(float4*)((float*)C + off) = make_float4(r[0], r[1], r[2], r[3]);
    } else {
      #pragma unroll
      for (int j = 0; j < 4; ++j){
        float sp = (r[j] > 20.f) ? r[j] : log1pf(__expf(r[j]));
        ((unsigned short*)C)[off + j] = f2us(sp);
      }
    }
  }
}

// ---------------- MFMA bf16 GEMM ----------------
// C[M,N] = epi( A[M,K](bf16,lda) @ W[N,K](bf16)^T + bias )
enum { G_PLAIN=0, G_GELU=1, G_RESID=2, G_FINAL=3 };
__global__ __launch_bounds__(256) void gemm_mfma_kernel(
    const unsigned short* __restrict__ A, int lda,
    const unsigned short* __restrict__ W,
    const float* __restrict__ bias,
    float* __restrict__ Cf, unsigned short* __restrict__ Cb,
    float* __restrict__ resid, void* __restrict__ outb,
    const int* __restrict__ flag, int N, int K, int mode)
{
  __shared__ unsigned short sA[64][56];   // 56-stride: 16B aligned, 2-way only
  __shared__ unsigned short sW[64][56];
  const int tid = threadIdx.x;
  const int w = tid >> 6, lane = tid & 63, quad = lane >> 4, l16 = lane & 15;
  const int m0 = blockIdx.y << 6, n0 = blockIdx.x << 6;
  const int lrow = tid >> 2, lk = (tid & 3) << 3;
  f32x4 acc[4] = {{0,0,0,0},{0,0,0,0},{0,0,0,0},{0,0,0,0}};
  for (int k0 = 0; k0 < K; k0 += 32){
    short8 av = *(const short8*)(A + (size_t)(m0 + lrow) * lda + k0 + lk);
    short8 wv = *(const short8*)(W + (size_t)(n0 + lrow) * K + k0 + lk);
    __syncthreads();
    *(short8*)&sA[lrow][lk] = av;
    *(short8*)&sW[lrow][lk] = wv;
    __syncthreads();
    short8 af = *(const short8*)&sA[w * 16 + l16][quad << 3];
    #pragma unroll
    for (int ns = 0; ns < 4; ++ns){
      short8 wf = *(const short8*)&sW[ns * 16 + l16][quad << 3];
      acc[ns] = __builtin_amdgcn_mfma_f32_16x16x32_bf16(af, wf, acc[ns], 0, 0, 0);
    }
  }
  #pragma unroll
  for (int ns = 0; ns < 4; ++ns){
    const int n = n0 + ns * 16 + l16;
    const float bv = bias ? bias[n] : 0.f;
    #pragma unroll
    for (int r = 0; r < 4; ++r){
      const int m = m0 + w * 16 + quad * 4 + r;
      const size_t off = (size_t)m * N + n;
      float v = acc[ns][r] + bv;
      if (mode == G_PLAIN) Cf[off] = v;
      else if (mode == G_GELU) Cb[off] = f2us(0.5f * v * (1.f + erff(v * 0.70710678118f)));
      else if (mode == G_RESID) resid[off] += v;
      else {
        float o = resid[off] + v;
        if (*flag) ((unsigned short*)outb)[off] = f2us(o);
        else ((float*)outb)[off] = o;
      }
    }
  }
}

// LayerNorm over D=256 (fp32 in, bf16 out).
__global__ __launch_bounds__(256) void ln_kernel(
    const float* __restrict__ xin,
    const float* __restrict__ w, const float* __restrict__ b,
    unsigned short* __restrict__ hout)
{
  const int row = blockIdx.x, tid = threadIdx.x;
  const size_t off = (size_t)row * DD + tid;
  float v = xin[off];
  float s = v, s2 = v * v;
  #pragma unroll
  for (int o = 32; o; o >>= 1){ s += __shfl_xor(s, o); s2 += __shfl_xor(s2, o); }
  __shared__ float ls[4], ls2[4];
  if ((tid & 63) == 0){ ls[tid >> 6] = s; ls2[tid >> 6] = s2; }
  __syncthreads();
  s  = ls[0] + ls[1] + ls[2] + ls[3];
  s2 = ls2[0] + ls2[1] + ls2[2] + ls2[3];
  const float mu  = s * (1.f / DD);
  const float var = s2 * (1.f / DD) - mu * mu;
  const float inv = rsqrtf(var + 1e-5f);
  hout[off] = f2us((v - mu) * inv * w[tid] + b[tid]);
}

// Depthwise causal conv (D_CONV=4) + bias + SiLU.  fp32 in/out.
__global__ __launch_bounds__(256) void conv_silu_kernel(
    const float* __restrict__ xz, const float* __restrict__ convw,
    const float* __restrict__ convb, float* __restrict__ xi, int rev)
{
  const int idx = blockIdx.x * 256 + threadIdx.x;
  const int c = idx & 511;
  const int t = (idx >> 9) & 2047;
  const int b = idx >> 20;
  float acc = convb[c];
  if (!rev){
    #pragma unroll
    for (int k = 0; k < 4; ++k){
      int tt = t - 3 + k;
      if (tt >= 0) acc += convw[c*4 + k] * xz[((size_t)(b*2048 + tt))*1024 + c];
    }
  } else {
    #pragma unroll
    for (int j = 0; j < 4; ++j){
      int tt = t + j;
      if (tt < 2048) acc += convw[c*4 + 3 - j] * xz[((size_t)(b*2048 + tt))*1024 + c];
    }
  }
  xi[idx] = acc / (1.f + __expf(-acc));
}

// ---------------- Chunked selective scan (n-in-registers) ----------------
// thread = one d; holds h[16]. block = (b, c, dg): d = dg*256+tid.
__global__ __launch_bounds__(256) void scan_part1_kernel(
    const unsigned short* __restrict__ dtb, const float* __restrict__ xib,
    const float* __restrict__ dblb, const float* __restrict__ Alog,
    float* __restrict__ dtsum, float* __restrict__ hend, int rev)
{
  const int bx = blockIdx.x;
  const int dg = bx & 1, c = (bx >> 1) & (NC - 1), b = bx >> 7;
  const int tid = threadIdx.x;
  const int d = dg * 256 + tid;
  __shared__ float sB[CT][16];
  for (int i = tid; i < CT * 16; i += 256){
    const int s = i >> 4, nn = i & 15;
    const int t = rev ? (LL - 1 - (c * CT + s)) : (c * CT + s);
    sB[s][nn] = dblb[(size_t)(b * LL + t) * 48 + 16 + nn];
  }
  float A[16];
  #pragma unroll
  for (int n = 0; n < 16; ++n) A[n] = -__expf(Alog[d * 16 + n]);
  __syncthreads();
  float h[16];
  #pragma unroll
  for (int n = 0; n < 16; ++n) h[n] = 0.f;
  float dts = 0.f;
  for (int s = 0; s < CT; ++s){
    const int t = rev ? (LL - 1 - (c * CT + s)) : (c * CT + s);
    const size_t row = (size_t)(b * LL + t);
    const float dtv = us2f(dtb[row * 512 + d]);
    const float uv = xib[row * 512 + d];
    const float dtu = dtv * uv;
    dts += dtv;
    float bl[16];
    #pragma unroll
    for (int q = 0; q < 4; ++q) *(float4*)&bl[q * 4] = *(const float4*)&sB[s][q * 4];
    #pragma unroll
    for (int n = 0; n < 16; ++n){
      const float e = __expf(dtv * A[n]);
      h[n] = h[n] * e + dtu * bl[n];
    }
  }
  const size_t base = ((size_t)((b * NC + c) * 512 + d)) * 16;
  #pragma unroll
  for (int q = 0; q < 4; ++q) *(float4*)&hend[base + q * 4] = *(const float4*)&h[q * 4];
  dtsum[(size_t)(b * NC + c) * 512 + d] = dts;
}

// thread = (b,d,n). Converts hend -> h_in in place (serial over chunks).
__global__ __launch_bounds__(256) void scan_combine_kernel(
    const float* __restrict__ dtsum, float* __restrict__ hend,
    const float* __restrict__ Alog)
{
  const unsigned g = blockIdx.x * 256u + threadIdx.x;   // 32768
  const int b = g >> 13, d = (g >> 4) & 511, n = g & 15;
  const float A = -__expf(Alog[d * 16 + n]);
  float h = 0.f;
  for (int c = 0; c < NC; ++c){
    const size_t sb = ((size_t)((b * NC + c) * 512 + d)) * 16 + n;
    const float e = __expf(dtsum[(size_t)(b * NC + c) * 512 + d] * A);
    const float he = hend[sb];
    hend[sb] = h;          // h_in for this chunk
    h = h * e + he;
  }
}

__global__ __launch_bounds__(256) void scan_part2_kernel(
    const unsigned short* __restrict__ dtb, const float* __restrict__ xib,
    const float* __restrict__ dblb, const float* __restrict__ xzb,
    const float* __restrict__ Alog, const float* __restrict__ Dp,
    const float* __restrict__ hin, unsigned short* __restrict__ ys, int rev)
{
  const int bx = blockIdx.x;
  const int dg = bx & 1, c = (bx >> 1) & (NC - 1), b = bx >> 7;
  const int tid = threadIdx.x;
  const int d = dg * 256 + tid;
  __shared__ float sB[CT][16];
  __shared__ float sC[CT][16];
  for (int i = tid; i < CT * 16; i += 256){
    const int s = i >> 4, nn = i & 15;
    const int t = rev ? (LL - 1 - (c * CT + s)) : (c * CT + s);
    sB[s][nn] = dblb[(size_t)(b * LL + t) * 48 + 16 + nn];
    sC[s][nn] = dblb[(size_t)(b * LL + t) * 48 + 32 + nn];
  }
  float A[16];
  #pragma unroll
  for (int n = 0; n < 16; ++n) A[n] = -__expf(Alog[d * 16 + n]);
  const float Dv = Dp[d];
  __syncthreads();
  float h[16];
  const size_t base = ((size_t)((b * NC + c) * 512 + d)) * 16;
  #pragma unroll
  for (int q = 0; q < 4; ++q) *(float4*)&h[q * 4] = *(const float4*)&hin[base + q * 4];
  for (int s = 0; s < CT; ++s){
    const int t = rev ? (LL - 1 - (c * CT + s)) : (c * CT + s);
    const size_t row = (size_t)(b * LL + t);
    const float dtv = us2f(dtb[row * 512 + d]);
    const float uv = xib[row * 512 + d];
    const float dtu = dtv * uv;
    float bl[16], cl[16];
    #pragma unroll
    for (int q = 0; q < 4; ++q){
      *(float4*)&bl[q * 4] = *(const float4*)&sB[s][q * 4];
      *(float4*)&cl[q * 4] = *(const float4*)&sC[s][q * 4];
    }
    float p = uv * Dv;
    #pragma unroll
    for (int n = 0; n < 16; ++n){
      const float e = __expf(dtv * A[n]);
      h[n] = h[n] * e + dtu * bl[n];
      p = fmaf(h[n], cl[n], p);
    }
    const float z = xzb[row * 1024 + 512 + d];
    ys[row * 512 + d] = f2us(p * (z / (1.f + __expf(-z))));
  }
}

// ---------------- MFMA flash attention ----------------
__global__ __launch_bounds__(256) void qk_prep_kernel(
    const float* __restrict__ qkv,
    unsigned short* __restrict__ Qb, unsigned short* __restrict__ Kb)
{
  const unsigned g = blockIdx.x * 256u + threadIdx.x;
  const int row = g >> 7;
  const int col = (g & 127) << 2;
  float4 v = *(const float4*)(qkv + (size_t)row * 768 + col);
  const int b = row >> 11, l = row & 2047;
  const int hc = col & 255;
  const int h = hc >> 6, d = hc & 63;
  unsigned short* dst = (col < 256) ? Qb : Kb;
  dst += ((size_t)((b * 4 + h) * 2048 + l)) * 64 + d;
  ushort4 o;
  o.x = f2us(v.x); o.y = f2us(v.y); o.z = f2us(v.z); o.w = f2us(v.w);
  *(ushort4*)dst = o;
}

__global__ __launch_bounds__(256) void v_prep_kernel(
    const float* __restrict__ qkv, unsigned short* __restrict__ Vt)
{
  const int kt = blockIdx.x;
  const int bh = blockIdx.y;
  const int b = bh >> 2, h = bh & 3;
  __shared__ float tile[64][68];
  #pragma unroll
  for (int rr = 0; rr < 4; ++rr){
    const int idx = (rr * 256 + threadIdx.x) * 4;
    const int key = idx >> 6, d = idx & 63;
    float4 v = *(const float4*)(qkv + ((size_t)(b * 2048 + kt * 64 + key)) * 768 + 512 + h * 64 + d);
    *(float4*)&tile[key][d] = v;
  }
  __syncthreads();
  #pragma unroll
  for (int rr = 0; rr < 8; ++rr){
    const int o2 = rr * 256 + threadIdx.x;
    const int d = o2 >> 5, k2 = (o2 & 31) << 1;
    ushort2 u;
    u.x = f2us(tile[k2][d]);
    u.y = f2us(tile[k2 + 1][d]);
    *(ushort2*)(Vt + (size_t)bh * 131072 + (size_t)d * 2048 + kt * 64 + k2) = u;
  }
}

__global__ __launch_bounds__(256) void attn_mfma_kernel(
    const unsigned short* __restrict__ Qb, const unsigned short* __restrict__ Kb,
    const unsigned short* __restrict__ Vt, unsigned short* __restrict__ outp)
{
  __shared__ unsigned short sK[64][72];
  __shared__ unsigned short sV[64][72];
  __shared__ unsigned short sP[4][16][72];
  const int tid = threadIdx.x;
  const int w = tid >> 6, lane = tid & 63, quad = lane >> 4, l16 = lane & 15;
  const int bh = blockIdx.y;
  const int q0 = blockIdx.x * 64;
  const size_t qkbase = (size_t)bh * 2048 * 64;

  const unsigned short* qp = Qb + qkbase + (size_t)(q0 + w * 16 + l16) * 64 + quad * 8;
  short8 qf0 = *(const short8*)qp;
  short8 qf1 = *(const short8*)(qp + 32);

  f32x4 o[4] = {{0,0,0,0},{0,0,0,0},{0,0,0,0},{0,0,0,0}};
  float mold[4] = {-INFINITY,-INFINITY,-INFINITY,-INFINITY};
  float lsum[4] = {0.f,0.f,0.f,0.f};

  for (int kt = 0; kt < LL; kt += 64){
    __syncthreads();
    #pragma unroll
    for (int r = 0; r < 2; ++r){
      const int idx = (r * 256 + tid) * 8;
      const int row = idx >> 6, c = idx & 63;
      *(short8*)&sK[row][c] = *(const short8*)(Kb + qkbase + (size_t)(kt + row) * 64 + c);
      *(short8*)&sV[row][c] = *(const short8*)(Vt + (size_t)bh * 131072 + (size_t)row * 2048 + kt + c);
    }
    __syncthreads();

    float p[4][4];
    #pragma unroll
    for (int sub = 0; sub < 4; ++sub){
      short8 bk0 = *(const short8*)&sK[sub * 16 + l16][quad * 8];
      short8 bk1 = *(const short8*)&sK[sub * 16 + l16][32 + quad * 8];
      f32x4 acc = {0,0,0,0};
      acc = __builtin_amdgcn_mfma_f32_16x16x32_bf16(qf0, bk0, acc, 0, 0, 0);
      acc = __builtin_amdgcn_mfma_f32_16x16x32_bf16(qf1, bk1, acc, 0, 0, 0);
      #pragma unroll
      for (int r = 0; r < 4; ++r) p[sub][r] = acc[r] * 0.125f;
    }
    #pragma unroll
    for (int r = 0; r < 4; ++r){
      float m = fmaxf(fmaxf(p[0][r], p[1][r]), fmaxf(p[2][r], p[3][r]));
      m = fmaxf(m, __shfl_xor(m, 1)); m = fmaxf(m, __shfl_xor(m, 2));
      m = fmaxf(m, __shfl_xor(m, 4)); m = fmaxf(m, __shfl_xor(m, 8));
      const float mnew = fmaxf(mold[r], m);
      const float alpha = __expf(mold[r] - mnew);
      const float pr0 = __expf(p[0][r] - mnew), pr1 = __expf(p[1][r] - mnew);
      const float pr2 = __expf(p[2][r] - mnew), pr3 = __expf(p[3][r] - mnew);
      p[0][r] = pr0; p[1][r] = pr1; p[2][r] = pr2; p[3][r] = pr3;
      float rs = pr0 + pr1 + pr2 + pr3;
      rs += __shfl_xor(rs, 1); rs += __shfl_xor(rs, 2);
      rs += __shfl_xor(rs, 4); rs += __shfl_xor(rs, 8);
      lsum[r] = lsum[r] * alpha + rs;
      mold[r] = mnew;
      #pragma unroll
      for (int nsub = 0; nsub < 4; ++nsub) o[nsub][r] *= alpha;
    }
    #pragma unroll
    for (int sub = 0; sub < 4; ++sub)
      #pragma unroll
      for (int r = 0; r < 4; ++r)
        sP[w][quad * 4 + r][sub * 16 + l16] = f2us(p[sub][r]);
    short8 pa0 = *(const short8*)&sP[w][l16][quad * 8];
    short8 pa1 = *(const short8*)&sP[w][l16][32 + quad * 8];
    #pragma unroll
    for (int nsub = 0; nsub < 4; ++nsub){
      short8 bv0 = *(const short8*)&sV[nsub * 16 + l16][quad * 8];
      short8 bv1 = *(const short8*)&sV[nsub * 16 + l16][32 + quad * 8];
      o[nsub] = __builtin_amdgcn_mfma_f32_16x16x32_bf16(pa0, bv0, o[nsub], 0, 0, 0);
      o[nsub] = __builtin_amdgcn_mfma_f32_16x16x32_bf16(pa1, bv1, o[nsub], 0, 0, 0);
    }
  }

  const int b = bh >> 2, h = bh & 3;
  #pragma unroll
  for (int r = 0; r < 4; ++r){
    const float invl = 1.f / lsum[r];
    const int q = q0 + w * 16 + quad * 4 + r;
    #pragma unroll
    for (int nsub = 0; nsub < 4; ++nsub)
      outp[((size_t)(b * 2048 + q)) * 256 + h * 64 + nsub * 16 + l16] = f2us(o[nsub][r] * invl);
  }
}

extern "C" void kernel_launch(void* const* d_in, const int* in_sizes, int n_in,
                              void* d_out, int out_size, void* d_ws, size_t ws_size,
                              hipStream_t stream)
{
  // 0 x | 1..9 mf_{Win,convw,convb,Wx,Wdt,bdt,Alog,D,Wout} | 10..18 mb_* |
  // 19..24 n1w..n3b | 25 Wqkv 26 bqkv 27 Wo 28 bo | 29 fc1w 30 fc1b 31 fc2w 32 fc2b
  static const bool needf[33] = {
    false, false,true,true,true,true,true,true,true,false,   // 0..9
    false,true,true,true,true,true,true,true,false,          // 10..18
    true,true,true,true,true,true,                           // 19..24 LN
    false,true,false,true,false,true,false,true };           // 25..32

  int* flag  = (int*)d_ws;
  float* wts = (float*)d_ws + 16;   // fp32 subset

  Srcs srcs;
  unsigned acc = 0, facc = 0;
  unsigned foff_h[33];
  for (int i = 1; i <= 32; ++i){
    srcs.p[i - 1] = d_in[i];
    srcs.off[i - 1] = acc;
    acc += (unsigned)in_sizes[i];
    if (needf[i]){ srcs.foff[i - 1] = facc; foff_h[i] = facc; facc += (unsigned)in_sizes[i]; }
    else { srcs.foff[i - 1] = 0xFFFFFFFFu; foff_h[i] = 0xFFFFFFFFu; }
  }
  srcs.off[32] = acc;
  const unsigned wtotal = acc;          // 1,665,792
  const unsigned ftot = (facc + 3u) & ~3u;

  unsigned short* wb16 = (unsigned short*)(wts + ftot);
  float* xf    = wts + ftot + wtotal / 2;       // wtotal even
  float* xzbuf = xf + 2097152;
  float* xibuf = xzbuf + 8388608;
  float* dblbuf= xibuf + 4194304;
  unsigned short* hb16 = (unsigned short*)(dblbuf + 393216);   // 2,097,152 shorts
  unsigned short* dtb16 = hb16 + 2097152;                      // 4,194,304 shorts
  float* hend  = (float*)(dtb16 + 4194304);                    // 2,097,152 f
  float* dtsum = hend + 2097152;                               //   131,072 f
  unsigned short* ysb16 = (unsigned short*)(dtsum + 131072);   // 4,194,304 shorts
  // attn overlays (dead buffers at attn time):
  unsigned short* Qb = dtb16;
  unsigned short* Kb = dtb16 + 2097152;
  unsigned short* Vt = (unsigned short*)hend;

  auto wp  = [&](int i){ return wts + foff_h[i]; };
  auto wp16= [&](int i){ return wb16 + srcs.off[i - 1]; };

  hipLaunchKernelGGL(probe_kernel, dim3(1), dim3(64), 0, stream,
      (const unsigned*)d_in[7], flag);
  hipLaunchKernelGGL(cvt_all_kernel, dim3((wtotal + 255) / 256), dim3(256), 0, stream,
      srcs, wts, wb16, flag, wtotal);
  hipLaunchKernelGGL(cvt_x_kernel, dim3(MTOT * DD / 256), dim3(256), 0, stream,
      d_in[0], xf, flag, (unsigned)(MTOT * DD));

  auto gemm16 = [&](const unsigned short* Ab, int lda, int iw, int ib,
                    float* Cf, unsigned short* Cb, float* resid, void* ob,
                    int N, int K, int mode){
    hipLaunchKernelGGL(gemm_mfma_kernel, dim3(N / 64, MTOT / 64), dim3(256), 0, stream,
        Ab, lda, wp16(iw), ib >= 0 ? wp(ib) : nullptr, Cf, Cb, resid, ob, flag, N, K, mode);
  };

  // LN1
  hipLaunchKernelGGL(ln_kernel, dim3(MTOT), dim3(256), 0, stream,
      xf, wp(19), wp(20), hb16);

  // Bidirectional Mamba
  for (int dir = 0; dir < 2; ++dir){
    const int o = dir ? 10 : 1;
    gemm16(hb16, 256, o + 0, -1, xzbuf, nullptr, nullptr, nullptr, 1024, 256, G_PLAIN);
    hipLaunchKernelGGL(conv_silu_kernel, dim3(MTOT * DINNER / 256), dim3(256), 0, stream,
        xzbuf, wp(o + 1), wp(o + 2), xibuf, dir);
    hipLaunchKernelGGL(gemm_small_kernel, dim3(1, MTOT / 64), dim3(256), 0, stream,
        xibuf, DINNER, wp(o + 3), (const float*)nullptr, (void*)dblbuf, 48, 512, 0);
    hipLaunchKernelGGL(gemm_small_kernel, dim3(8, MTOT / 64), dim3(256), 0, stream,
        dblbuf, 48, wp(o + 4), wp(o + 5), (void*)dtb16, 512, 16, 1);
    hipLaunchKernelGGL(scan_part1_kernel, dim3(4 * NC * 2), dim3(256), 0, stream,
        dtb16, xibuf, dblbuf, wp(o + 6), dtsum, hend, dir);
    hipLaunchKernelGGL(scan_combine_kernel, dim3(128), dim3(256), 0, stream,
        dtsum, hend, wp(o + 6));
    hipLaunchKernelGGL(scan_part2_kernel, dim3(4 * NC * 2), dim3(256), 0, stream,
        dtb16, xibuf, dblbuf, xzbuf, wp(o + 6), wp(o + 7), hend, ysb16, dir);
    gemm16(ysb16, 512, o + 8, -1, nullptr, nullptr, xf, nullptr, 256, 512, G_RESID);
  }

  // Attention
  hipLaunchKernelGGL(ln_kernel, dim3(MTOT), dim3(256), 0, stream,
      xf, wp(21), wp(22), hb16);
  gemm16(hb16, 256, 25, 26, xzbuf, nullptr, nullptr, nullptr, 768, 256, G_PLAIN);
  hipLaunchKernelGGL(qk_prep_kernel, dim3(4096), dim3(256), 0, stream,
      xzbuf, Qb, Kb);
  hipLaunchKernelGGL(v_prep_kernel, dim3(32, 16), dim3(256), 0, stream,
      xzbuf, Vt);
  hipLaunchKernelGGL(attn_mfma_kernel, dim3(32, 16), dim3(256), 0, stream,
      Qb, Kb, Vt, ysb16);
  gemm16(ysb16, 256, 27, 28, nullptr, nullptr, xf, nullptr, 256, 256, G_RESID);

  // MLP
  hipLaunchKernelGGL(ln_kernel, dim3(MTOT), dim3(256), 0, stream,
      xf, wp(23), wp(24), hb16);
  gemm16(hb16, 256, 29, 30, nullptr, (unsigned short*)xzbuf, nullptr, nullptr, 1024, 256, G_GELU);
  gemm16((unsigned short*)xzbuf, 1024, 31, 32, nullptr, nullptr, xf, d_out, 256, 1024, G_FINAL);
}